// Round 4
// baseline (204.800 us; speedup 1.0000x reference)
//
#include <hip/hip_runtime.h>

#define NUM_SEG 32
#define MUL 128
#define D 3
#define NUM_PATHS 64
#define ROW (NUM_SEG * MUL * D)   // 12288 floats per batch row
#define SEGF (MUL * D)            // 384 floats per segment row

typedef float v4f __attribute__((ext_vector_type(4)));  // clang vector: builtin-compatible

__global__ __launch_bounds__(256) void ftp_kernel(
    const float* __restrict__ x0, const float* __restrict__ x1,
    const float* __restrict__ coeff, const int* __restrict__ idx0,
    const int* __restrict__ idx1, const int* __restrict__ idx2,
    float* __restrict__ out)
{
    const int b   = blockIdx.x;
    const int tid = threadIdx.x;

    __shared__ float s_m[NUM_PATHS][D * D];                // m[p][i*3+k]
    __shared__ int   s_seg0[NUM_PATHS];                    // idx0 per path
    __shared__ unsigned char s_plist[NUM_SEG][NUM_PATHS];  // per-segment path lists
    __shared__ int   s_cnt[NUM_SEG];

    if (tid < NUM_SEG) s_cnt[tid] = 0;
    __syncthreads();

    if (tid < NUM_PATHS) {
        const int p  = tid;
        const int i1 = idx1[p];
        s_seg0[p]    = idx0[p];
        const int s2 = idx2[p];
        const int pos = atomicAdd(&s_cnt[s2], 1);
        s_plist[s2][pos] = (unsigned char)p;

        const float* x1row = x1 + (size_t)b * (NUM_SEG * D) + i1 * D;
        const float xj0 = x1row[0], xj1 = x1row[1], xj2 = x1row[2];
        const float* cf = coeff + p * 27;   // coeff[p][i][j][k]
        #pragma unroll
        for (int i = 0; i < D; ++i) {
            #pragma unroll
            for (int k = 0; k < D; ++k) {
                s_m[p][i * 3 + k] = xj0 * cf[i * 9 + 0 + k]
                                  + xj1 * cf[i * 9 + 3 + k]
                                  + xj2 * cf[i * 9 + 6 + k];
            }
        }
    }
    __syncthreads();

    // Thread owns a u-quad: 4 consecutive u -> 12 floats -> 3 aligned float4s.
    const int q  = tid & 31;        // quad index within segment (u = 4q..4q+3)
    const int ss = tid >> 5;        // segment slot: 8 concurrent segments
    const float* __restrict__ x0base = x0 + (size_t)b * ROW + q * 12;
    float* __restrict__ outb = out + (size_t)b * ROW + q * 12;

    for (int s = ss; s < NUM_SEG; s += 8) {
        float acc[4][3];
        #pragma unroll
        for (int u = 0; u < 4; ++u)
            #pragma unroll
            for (int k = 0; k < 3; ++k) acc[u][k] = 0.f;

        const int n = s_cnt[s];
        for (int t = 0; t < n; ++t) {
            const int p = s_plist[s][t];
            const v4f* __restrict__ src =
                (const v4f*)(x0base + s_seg0[p] * SEGF);
            const v4f A = src[0], B = src[1], C = src[2];
            const float* m = s_m[p];   // half-wave-uniform -> LDS broadcast

            // triplets: u0=(A.x,A.y,A.z) u1=(A.w,B.x,B.y) u2=(B.z,B.w,C.x) u3=(C.y,C.z,C.w)
            #pragma unroll
            for (int k = 0; k < 3; ++k) {
                const float m0 = m[0 + k], m1 = m[3 + k], m2 = m[6 + k];
                acc[0][k] += A.x * m0 + A.y * m1 + A.z * m2;
                acc[1][k] += A.w * m0 + B.x * m1 + B.y * m2;
                acc[2][k] += B.z * m0 + B.w * m1 + C.x * m2;
                acc[3][k] += C.y * m0 + C.z * m1 + C.w * m2;
            }
        }

        v4f* __restrict__ dst = (v4f*)(outb + s * SEGF);
        v4f O0 = {acc[0][0], acc[0][1], acc[0][2], acc[1][0]};
        v4f O1 = {acc[1][1], acc[1][2], acc[2][0], acc[2][1]};
        v4f O2 = {acc[2][2], acc[3][0], acc[3][1], acc[3][2]};
        __builtin_nontemporal_store(O0, dst + 0);
        __builtin_nontemporal_store(O1, dst + 1);
        __builtin_nontemporal_store(O2, dst + 2);
    }
}

extern "C" void kernel_launch(void* const* d_in, const int* in_sizes, int n_in,
                              void* d_out, int out_size, void* d_ws, size_t ws_size,
                              hipStream_t stream) {
    const float* x0    = (const float*)d_in[0];
    const float* x1    = (const float*)d_in[1];
    const float* coeff = (const float*)d_in[2];
    const int*   idx0  = (const int*)d_in[3];
    const int*   idx1  = (const int*)d_in[4];
    const int*   idx2  = (const int*)d_in[5];
    float* out = (float*)d_out;

    const int B = in_sizes[0] / ROW;
    ftp_kernel<<<B, 256, 0, stream>>>(x0, x1, coeff, idx0, idx1, idx2, out);
}

// Round 5
// 201.376 us; speedup vs baseline: 1.0170x; 1.0170x over previous
//
#include <hip/hip_runtime.h>

#define NUM_SEG 32
#define MUL 128
#define D 3
#define NUM_PATHS 64
#define ROW (NUM_SEG * MUL * D)   // 12288 floats per batch row
#define SEGF (MUL * D)            // 384 floats per segment row
#define RPB 4                     // batch rows per block

typedef float v2f __attribute__((ext_vector_type(2)));
typedef float v4f __attribute__((ext_vector_type(4)));

// ws layout: [0..63] packed schedule (seg0 | p<<8 | flush<<16, flush=255 -> none),
//            [64] = n_empty, [65..96] = empty segment ids
__global__ __launch_bounds__(64) void setup_kernel(
    const int* __restrict__ idx0, const int* __restrict__ idx2,
    int* __restrict__ ws)
{
    __shared__ int s2[NUM_PATHS];
    __shared__ int ord[NUM_PATHS];
    __shared__ int has[NUM_SEG];
    __shared__ int ecnt;
    const int t = threadIdx.x;
    if (t < NUM_SEG) has[t] = 0;
    if (t == 0) ecnt = 0;
    s2[t] = idx2[t];
    __syncthreads();
    // stable rank by (idx2, p): all keys distinct -> permutation
    const int key = s2[t] * 64 + t;
    int rank = 0;
    for (int p = 0; p < NUM_PATHS; ++p) rank += ((s2[p] * 64 + p) < key);
    ord[rank] = t;
    has[s2[t]] = 1;
    __syncthreads();
    const int p = ord[t];
    const int fl = (t == NUM_PATHS - 1 || s2[ord[t + 1]] != s2[p]) ? s2[p] : 255;
    ws[t] = (idx0[p] & 255) | ((p & 255) << 8) | (fl << 16);
    if (t < NUM_SEG && !has[t]) {
        const int slot = atomicAdd(&ecnt, 1);
        ws[65 + slot] = t;
    }
    __syncthreads();
    if (t == 0) ws[64] = ecnt;
}

__global__ __launch_bounds__(256) void ftp_main(
    const float* __restrict__ x0, const float* __restrict__ x1,
    const float* __restrict__ coeff, const int* __restrict__ idx1,
    const int* __restrict__ ws, float* __restrict__ out)
{
    __shared__ float s_m[RPB][NUM_PATHS][12];  // 48B stride per matrix
    __shared__ int s_sched[NUM_PATHS];
    __shared__ int s_emp[33];

    const int tid = threadIdx.x;
    const int b0 = blockIdx.x * RPB;

    if (tid < 64) s_sched[tid] = ws[tid];
    else if (tid < 97) s_emp[tid - 64] = ws[tid];   // s_emp[0]=ne, s_emp[1..]=list

    // m[r][p][i*3+k] = sum_j x1[b0+r, idx1[p], j] * coeff[p,i,j,k] — one (r,p) per thread
    {
        const int p = tid & 63, r = tid >> 6;
        const int b = b0 + r;
        const int i1 = idx1[p];
        const float* xr = x1 + (size_t)b * (NUM_SEG * D) + i1 * D;
        const float j0 = xr[0], j1 = xr[1], j2 = xr[2];
        const float* cf = coeff + p * 27;
        #pragma unroll
        for (int i = 0; i < D; ++i)
            #pragma unroll
            for (int k = 0; k < D; ++k)
                s_m[r][p][i * 3 + k] = j0 * cf[i * 9 + k]
                                     + j1 * cf[i * 9 + 3 + k]
                                     + j2 * cf[i * 9 + 6 + k];
    }
    __syncthreads();

    // thread owns u-pair q (6 floats), row r; wave = 1 row -> uniform-ish
    const int q = tid & 63;
    const int r = tid >> 6;
    const int b = b0 + r;
    const float* __restrict__ xb = x0 + (size_t)b * ROW + q * 6;
    float* __restrict__ ob = out + (size_t)b * ROW + q * 6;

    float a00 = 0, a01 = 0, a02 = 0, a10 = 0, a11 = 0, a12 = 0;
    #pragma unroll
    for (int t = 0; t < NUM_PATHS; ++t) {
        const int e = s_sched[t];             // ds_read, immediate offset
        const int seg0 = e & 255;
        const int p = (e >> 8) & 255;
        const int fl = e >> 16;
        const float* xs = xb + seg0 * SEGF;   // 8B-aligned (q*24)
        const v2f L0 = *(const v2f*)(xs + 0); // u0i0 u0i1
        const v2f L1 = *(const v2f*)(xs + 2); // u0i2 u1i0
        const v2f L2 = *(const v2f*)(xs + 4); // u1i1 u1i2
        const float* m = s_m[r][p];           // half-wave broadcast
        a00 += L0.x * m[0] + L0.y * m[3] + L1.x * m[6];
        a01 += L0.x * m[1] + L0.y * m[4] + L1.x * m[7];
        a02 += L0.x * m[2] + L0.y * m[5] + L1.x * m[8];
        a10 += L1.y * m[0] + L2.x * m[3] + L2.y * m[6];
        a11 += L1.y * m[1] + L2.x * m[4] + L2.y * m[7];
        a12 += L1.y * m[2] + L2.x * m[5] + L2.y * m[8];
        if (fl != 255) {                      // block-uniform branch
            float* o = ob + fl * SEGF;
            v2f O0 = {a00, a01}, O1 = {a02, a10}, O2 = {a11, a12};
            *(v2f*)(o + 0) = O0;
            *(v2f*)(o + 2) = O1;
            *(v2f*)(o + 4) = O2;
            a00 = a01 = a02 = a10 = a11 = a12 = 0.f;
        }
    }
    // segments never referenced by idx2 -> zeros
    const int ne = s_emp[0];
    for (int i = 0; i < ne; ++i) {
        float* o = ob + s_emp[1 + i] * SEGF;
        v2f Z = {0.f, 0.f};
        *(v2f*)(o + 0) = Z;
        *(v2f*)(o + 2) = Z;
        *(v2f*)(o + 4) = Z;
    }
}

extern "C" void kernel_launch(void* const* d_in, const int* in_sizes, int n_in,
                              void* d_out, int out_size, void* d_ws, size_t ws_size,
                              hipStream_t stream) {
    const float* x0    = (const float*)d_in[0];
    const float* x1    = (const float*)d_in[1];
    const float* coeff = (const float*)d_in[2];
    const int*   idx0  = (const int*)d_in[3];
    const int*   idx1  = (const int*)d_in[4];
    const int*   idx2  = (const int*)d_in[5];
    float* out = (float*)d_out;
    int*   ws  = (int*)d_ws;

    const int B = in_sizes[0] / ROW;
    setup_kernel<<<1, 64, 0, stream>>>(idx0, idx2, ws);
    ftp_main<<<B / RPB, 256, 0, stream>>>(x0, x1, coeff, idx1, ws, out);
}

// Round 6
// 190.294 us; speedup vs baseline: 1.0762x; 1.0582x over previous
//
#include <hip/hip_runtime.h>

#define NUM_SEG 32
#define MUL 128
#define D 3
#define NUM_PATHS 64
#define ROW (NUM_SEG * MUL * D)   // 12288 floats per batch row
#define SEGF (MUL * D)            // 384 floats per full segment row
#define HALF_F4 1536              // float4s per half-image: 32 segs * 48
#define SEG_HF 192                // floats per segment in a u-half (64 u * 3)

typedef float v2f __attribute__((ext_vector_type(2)));
typedef float v4f __attribute__((ext_vector_type(4)));

__global__ __launch_bounds__(256) void ftp_kernel(
    const float* __restrict__ x0, const float* __restrict__ x1,
    const float* __restrict__ coeff, const int* __restrict__ idx0,
    const int* __restrict__ idx1, const int* __restrict__ idx2,
    float* __restrict__ out)
{
    const int bid = blockIdx.x;
    const int b   = bid >> 1;          // batch row
    const int h   = bid & 1;           // u-half: 0 -> u<64, 1 -> u>=64
    const int tid = threadIdx.x;

    __shared__ v4f   s_x0[HALF_F4];                      // 24 KB: half row, all segs
    __shared__ float s_m[NUM_PATHS][9];                  // m[p][i*3+k]
    __shared__ unsigned short s_pe[NUM_SEG][NUM_PATHS];  // packed seg0 | p<<8
    __shared__ int   s_cnt[NUM_SEG];

    if (tid < NUM_SEG) s_cnt[tid] = 0;
    __syncthreads();

    // ---- stage u-half of x0 row: 6 contiguous-f4 loads/thread, exactly once ----
    const v4f* __restrict__ src = (const v4f*)(x0 + (size_t)b * ROW);
    #pragma unroll
    for (int j = 0; j < 6; ++j) {
        const int f     = j * 256 + tid;     // [0,1536)
        const int seg   = f / 48;            // const-div -> magic mul
        const int inner = f - seg * 48;
        s_x0[f] = src[seg * 96 + h * 48 + inner];
    }

    // ---- wave 0: build m-matrices + packed per-segment schedule ----
    if (tid < NUM_PATHS) {
        const int p  = tid;
        const int s0 = idx0[p];
        const int i1 = idx1[p];
        const int s2 = idx2[p];
        const int pos = atomicAdd(&s_cnt[s2], 1);
        s_pe[s2][pos] = (unsigned short)(s0 | (p << 8));

        const float* xr = x1 + (size_t)b * (NUM_SEG * D) + i1 * D;
        const float j0 = xr[0], j1 = xr[1], j2 = xr[2];
        const float* cf = coeff + p * 27;    // coeff[p][i][j][k]
        #pragma unroll
        for (int i = 0; i < D; ++i)
            #pragma unroll
            for (int k = 0; k < D; ++k)
                s_m[p][i * 3 + k] = j0 * cf[i * 9 + k]
                                  + j1 * cf[i * 9 + 3 + k]
                                  + j2 * cf[i * 9 + 6 + k];
    }
    __syncthreads();

    // ---- compute: thread owns (seg-slot ss, u-pair q); 4 segs per thread ----
    const int q  = tid & 31;           // u-pair: local u = 2q, 2q+1
    const int ss = tid >> 5;           // 8 concurrent segment slots
    float* __restrict__ ob = out + (size_t)b * ROW + h * SEG_HF + q * 6;
    const float* __restrict__ sx = (const float*)s_x0;

    #pragma unroll
    for (int si = 0; si < 4; ++si) {
        const int s = ss + si * 8;
        float a00 = 0, a01 = 0, a02 = 0, a10 = 0, a11 = 0, a12 = 0;
        const int n = s_cnt[s];
        for (int t = 0; t < n; ++t) {
            const int e = s_pe[s][t];          // one ds_read: seg0 | p<<8
            const float* xs = sx + (e & 255) * SEG_HF + q * 6;
            const float u00 = xs[0], u01 = xs[1], u02 = xs[2];
            const float u10 = xs[3], u11 = xs[4], u12 = xs[5];
            const float* m = s_m[e >> 8];      // half-wave-uniform broadcast
            a00 += u00 * m[0] + u01 * m[3] + u02 * m[6];
            a01 += u00 * m[1] + u01 * m[4] + u02 * m[7];
            a02 += u00 * m[2] + u01 * m[5] + u02 * m[8];
            a10 += u10 * m[0] + u11 * m[3] + u12 * m[6];
            a11 += u10 * m[1] + u11 * m[4] + u12 * m[7];
            a12 += u10 * m[2] + u11 * m[5] + u12 * m[8];
        }
        float* o = ob + s * SEGF;              // wave: 2 bursts of 768B contiguous
        v2f O0 = {a00, a01}, O1 = {a02, a10}, O2 = {a11, a12};
        *(v2f*)(o + 0) = O0;
        *(v2f*)(o + 2) = O1;
        *(v2f*)(o + 4) = O2;
    }
}

extern "C" void kernel_launch(void* const* d_in, const int* in_sizes, int n_in,
                              void* d_out, int out_size, void* d_ws, size_t ws_size,
                              hipStream_t stream) {
    const float* x0    = (const float*)d_in[0];
    const float* x1    = (const float*)d_in[1];
    const float* coeff = (const float*)d_in[2];
    const int*   idx0  = (const int*)d_in[3];
    const int*   idx1  = (const int*)d_in[4];
    const int*   idx2  = (const int*)d_in[5];
    float* out = (float*)d_out;

    const int B = in_sizes[0] / ROW;
    ftp_kernel<<<B * 2, 256, 0, stream>>>(x0, x1, coeff, idx0, idx1, idx2, out);
}